// Round 4
// baseline (118.039 us; speedup 1.0000x reference)
//
#include <hip/hip_runtime.h>

// Problem: B=2, C=6 (DTI lower-tri), H=W=D=64. fp32 in, fp32 out.
// out[b,c,x,y,z] = (R^T M R)[I[c],J[c]]
//   M = 3x3 symmetric from trilinear-warped DTI (border clamp, align_corners)
//   R = orthogonal polar factor of J = I + du/dx  (== U @ Vh of SVD(J))
// Polar factor via scaled Newton in fp64 (near-singular J voxels need it to
// match the float64 np reference); warp + Jacobian staging in fp32.
#define NVOX 262144          // 64^3
#define TOTAL (2 * NVOX)     // B * H * W * D threads

__global__ __launch_bounds__(256)
void warpdti_kernel(const float* __restrict__ dti,
                    const float* __restrict__ ddf,
                    float* __restrict__ out)
{
    const int idx = blockIdx.x * 256 + threadIdx.x;   // exactly TOTAL threads
    const int b = idx >> 18;
    const int r = idx & (NVOX - 1);
    const int x = r >> 12;
    const int y = (r >> 6) & 63;
    const int z = r & 63;

    const float* db = ddf + (size_t)b * 3 * NVOX;

    // ---------------- displacement at center ----------------
    const float ux = db[r];
    const float uy = db[NVOX + r];
    const float uz = db[2 * NVOX + r];

    // ---------------- trilinear warp, border padding (fp32) ----------------
    const float cx = fminf(fmaxf((float)x + ux, 0.0f), 63.0f);
    const float cy = fminf(fmaxf((float)y + uy, 0.0f), 63.0f);
    const float cz = fminf(fmaxf((float)z + uz, 0.0f), 63.0f);
    const float fx0 = floorf(cx), fy0 = floorf(cy), fz0 = floorf(cz);
    const float fx = cx - fx0, fy = cy - fy0, fz = cz - fz0;
    const int x0 = (int)fx0, y0 = (int)fy0, z0 = (int)fz0;
    const int x1 = min(x0 + 1, 63), y1 = min(y0 + 1, 63), z1 = min(z0 + 1, 63);

    const float gx = 1.0f - fx, gy = 1.0f - fy, gz = 1.0f - fz;
    const float w000 = gx * gy * gz, w001 = gx * gy * fz;
    const float w010 = gx * fy * gz, w011 = gx * fy * fz;
    const float w100 = fx * gy * gz, w101 = fx * gy * fz;
    const float w110 = fx * fy * gz, w111 = fx * fy * fz;

    const int o000 = (x0 * 64 + y0) * 64 + z0, o001 = (x0 * 64 + y0) * 64 + z1;
    const int o010 = (x0 * 64 + y1) * 64 + z0, o011 = (x0 * 64 + y1) * 64 + z1;
    const int o100 = (x1 * 64 + y0) * 64 + z0, o101 = (x1 * 64 + y0) * 64 + z1;
    const int o110 = (x1 * 64 + y1) * 64 + z0, o111 = (x1 * 64 + y1) * 64 + z1;

    const float* tb = dti + (size_t)b * 6 * NVOX;
    float m[6];
#pragma unroll
    for (int c = 0; c < 6; ++c) {
        const float* tc = tb + c * NVOX;
        m[c] = w000 * tc[o000] + w001 * tc[o001]
             + w010 * tc[o010] + w011 * tc[o011]
             + w100 * tc[o100] + w101 * tc[o101]
             + w110 * tc[o110] + w111 * tc[o111];
    }

    // -------- Jacobian J = I + du/dx, fp64 (np.gradient semantics) ----------
    const int xm = max(x - 1, 0), xp = min(x + 1, 63);
    const int ym = max(y - 1, 0), yp = min(y + 1, 63);
    const int zm = max(z - 1, 0), zp = min(z + 1, 63);
    const double sx = (xp - xm == 2) ? 0.5 : 1.0;
    const double sy = (yp - ym == 2) ? 0.5 : 1.0;
    const double sz = (zp - zm == 2) ? 0.5 : 1.0;

    double X[3][3];
#pragma unroll
    for (int i = 0; i < 3; ++i) {
        const float* ui = db + i * NVOX;
        X[i][0] = ((double)ui[(xp * 64 + y) * 64 + z]
                 - (double)ui[(xm * 64 + y) * 64 + z]) * sx + (i == 0 ? 1.0 : 0.0);
        X[i][1] = ((double)ui[(x * 64 + yp) * 64 + z]
                 - (double)ui[(x * 64 + ym) * 64 + z]) * sy + (i == 1 ? 1.0 : 0.0);
        X[i][2] = ((double)ui[(x * 64 + y) * 64 + zp]
                 - (double)ui[(x * 64 + y) * 64 + zm]) * sz + (i == 2 ? 1.0 : 0.0);
    }

    // -------- polar factor via scaled Newton in fp64 (overflow-proof) -------
    // X <- c1*X + c2*cof(X); c1 = 0.5*sqrt(t/|d|), c2 = 0.5*sgn(d)/sqrt(t|d|),
    // t = ||cof||_F/||X||_F. Max-abs normalize each iter (scale-invariant).
#pragma unroll
    for (int it = 0; it < 14; ++it) {
        double mx = 0.0;
#pragma unroll
        for (int i = 0; i < 3; ++i)
#pragma unroll
            for (int j = 0; j < 3; ++j) mx = fmax(mx, fabs(X[i][j]));
        const double s = 1.0 / fmax(mx, 1e-300);
#pragma unroll
        for (int i = 0; i < 3; ++i)
#pragma unroll
            for (int j = 0; j < 3; ++j) X[i][j] *= s;

        const double C00 = X[1][1] * X[2][2] - X[1][2] * X[2][1];
        const double C01 = X[1][2] * X[2][0] - X[1][0] * X[2][2];
        const double C02 = X[1][0] * X[2][1] - X[1][1] * X[2][0];
        const double C10 = X[0][2] * X[2][1] - X[0][1] * X[2][2];
        const double C11 = X[0][0] * X[2][2] - X[0][2] * X[2][0];
        const double C12 = X[0][1] * X[2][0] - X[0][0] * X[2][1];
        const double C20 = X[0][1] * X[1][2] - X[0][2] * X[1][1];
        const double C21 = X[0][2] * X[1][0] - X[0][0] * X[1][2];
        const double C22 = X[0][0] * X[1][1] - X[0][1] * X[1][0];
        const double det = X[0][0] * C00 + X[0][1] * C01 + X[0][2] * C02;

        const double n2 = X[0][0]*X[0][0] + X[0][1]*X[0][1] + X[0][2]*X[0][2]
                        + X[1][0]*X[1][0] + X[1][1]*X[1][1] + X[1][2]*X[1][2]
                        + X[2][0]*X[2][0] + X[2][1]*X[2][1] + X[2][2]*X[2][2];
        const double a2 = C00*C00 + C01*C01 + C02*C02
                        + C10*C10 + C11*C11 + C12*C12
                        + C20*C20 + C21*C21 + C22*C22;

        const double t  = fmax(sqrt(a2 / n2), 1e-150);
        const double ad = fmax(fabs(det), 1e-280);
        const double sg = (det < 0.0) ? -1.0 : 1.0;
        const double c1 = 0.5 * sqrt(t / ad);
        const double c2 = 0.5 * sg / sqrt(t * ad);

        X[0][0] = c1 * X[0][0] + c2 * C00;  X[0][1] = c1 * X[0][1] + c2 * C01;  X[0][2] = c1 * X[0][2] + c2 * C02;
        X[1][0] = c1 * X[1][0] + c2 * C10;  X[1][1] = c1 * X[1][1] + c2 * C11;  X[1][2] = c1 * X[1][2] + c2 * C12;
        X[2][0] = c1 * X[2][0] + c2 * C20;  X[2][1] = c1 * X[2][1] + c2 * C21;  X[2][2] = c1 * X[2][2] + c2 * C22;
    }

    // ---------------- A = R^T * M * R (fp64) ----------------
    const double M3[3][3] = {{(double)m[0], (double)m[1], (double)m[3]},
                             {(double)m[1], (double)m[2], (double)m[4]},
                             {(double)m[3], (double)m[4], (double)m[5]}};
    double T[3][3];
#pragma unroll
    for (int i = 0; i < 3; ++i)
#pragma unroll
        for (int j = 0; j < 3; ++j)
            T[i][j] = X[0][i] * M3[0][j] + X[1][i] * M3[1][j] + X[2][i] * M3[2][j];

    double A[3][3];
#pragma unroll
    for (int i = 0; i < 3; ++i)
#pragma unroll
        for (int j = 0; j < 3; ++j)
            A[i][j] = T[i][0] * X[0][j] + T[i][1] * X[1][j] + T[i][2] * X[2][j];

    // ---------------- emit lower-tri (B,6,H,W,D) fp32 ----------------
    float* ob = out + (size_t)b * 6 * NVOX;
    ob[0 * NVOX + r] = (float)A[0][0];
    ob[1 * NVOX + r] = (float)A[1][0];
    ob[2 * NVOX + r] = (float)A[1][1];
    ob[3 * NVOX + r] = (float)A[2][0];
    ob[4 * NVOX + r] = (float)A[2][1];
    ob[5 * NVOX + r] = (float)A[2][2];
}

extern "C" void kernel_launch(void* const* d_in, const int* in_sizes, int n_in,
                              void* d_out, int out_size, void* d_ws, size_t ws_size,
                              hipStream_t stream) {
    const float* dti = (const float*)d_in[0];
    const float* ddf = (const float*)d_in[1];
    float* out = (float*)d_out;
    warpdti_kernel<<<TOTAL / 256, 256, 0, stream>>>(dti, ddf, out);
}

// Round 5
// 113.663 us; speedup vs baseline: 1.0385x; 1.0385x over previous
//
#include <hip/hip_runtime.h>

// Problem: B=2, C=6 (DTI lower-tri), H=W=D=64. fp32 in, fp32 out.
// out[b,c,x,y,z] = (R^T M R)[I[c],J[c]]
//   M = 3x3 symmetric from trilinear-warped DTI (border clamp, align_corners)
//   R = orthogonal polar factor of J = I + du/dx  (== U @ Vh of SVD(J))
// Fast path: fp32 scaled-Newton polar (8 iters). Lanes with cond(J) > 1e4
// (~1e-4 of voxels) redo in fp64 (14 iters, normalized) to match the float64
// numpy reference. z == lane, so z-neighbor diffs come from __shfl.
#define NVOX 262144          // 64^3
#define TOTAL (2 * NVOX)     // B * H * W * D threads

__global__ __launch_bounds__(256)
void warpdti_kernel(const float* __restrict__ dti,
                    const float* __restrict__ ddf,
                    float* __restrict__ out)
{
    const int idx = blockIdx.x * 256 + threadIdx.x;   // exactly TOTAL threads
    const int b = idx >> 18;
    const int r = idx & (NVOX - 1);
    const int x = r >> 12;
    const int y = (r >> 6) & 63;
    const int z = r & 63;              // == threadIdx.x & 63 == lane

    const float* db = ddf + (size_t)b * 3 * NVOX;

    // ---------------- displacement at center ----------------
    const float ux = db[r];
    const float uy = db[NVOX + r];
    const float uz = db[2 * NVOX + r];

    // ---------------- trilinear warp, border padding (fp32) ----------------
    const float cx = fminf(fmaxf((float)x + ux, 0.0f), 63.0f);
    const float cy = fminf(fmaxf((float)y + uy, 0.0f), 63.0f);
    const float cz = fminf(fmaxf((float)z + uz, 0.0f), 63.0f);
    const float fx0 = floorf(cx), fy0 = floorf(cy), fz0 = floorf(cz);
    const float fx = cx - fx0, fy = cy - fy0, fz = cz - fz0;
    const int x0 = (int)fx0, y0 = (int)fy0, z0 = (int)fz0;
    const int x1 = min(x0 + 1, 63), y1 = min(y0 + 1, 63), z1 = min(z0 + 1, 63);

    const float gx = 1.0f - fx, gy = 1.0f - fy, gz = 1.0f - fz;
    const float w000 = gx * gy * gz, w001 = gx * gy * fz;
    const float w010 = gx * fy * gz, w011 = gx * fy * fz;
    const float w100 = fx * gy * gz, w101 = fx * gy * fz;
    const float w110 = fx * fy * gz, w111 = fx * fy * fz;

    const int o000 = (x0 * 64 + y0) * 64 + z0, o001 = (x0 * 64 + y0) * 64 + z1;
    const int o010 = (x0 * 64 + y1) * 64 + z0, o011 = (x0 * 64 + y1) * 64 + z1;
    const int o100 = (x1 * 64 + y0) * 64 + z0, o101 = (x1 * 64 + y0) * 64 + z1;
    const int o110 = (x1 * 64 + y1) * 64 + z0, o111 = (x1 * 64 + y1) * 64 + z1;

    const float* tb = dti + (size_t)b * 6 * NVOX;
    float m[6];
#pragma unroll
    for (int c = 0; c < 6; ++c) {
        const float* tc = tb + c * NVOX;
        m[c] = w000 * tc[o000] + w001 * tc[o001]
             + w010 * tc[o010] + w011 * tc[o011]
             + w100 * tc[o100] + w101 * tc[o101]
             + w110 * tc[o110] + w111 * tc[o111];
    }

    // -------- Jacobian J = I + du/dx (np.gradient semantics), fp32 ---------
    const int xm = max(x - 1, 0), xp = min(x + 1, 63);
    const int ym = max(y - 1, 0), yp = min(y + 1, 63);
    const int zm = max(z - 1, 0), zp = min(z + 1, 63);
    const float sx = (xp - xm == 2) ? 0.5f : 1.0f;
    const float sy = (yp - ym == 2) ? 0.5f : 1.0f;
    const float sz = (zp - zm == 2) ? 0.5f : 1.0f;

    const float uc0 = ux, uc1 = uy, uc2 = uz;
    float P[3][3];
#pragma unroll
    for (int i = 0; i < 3; ++i) {
        const float* ui = db + i * NVOX;
        const float ctr = (i == 0) ? uc0 : (i == 1) ? uc1 : uc2;
        P[i][0] = (ui[(xp * 64 + y) * 64 + z] - ui[(xm * 64 + y) * 64 + z]) * sx
                + (i == 0 ? 1.0f : 0.0f);
        P[i][1] = (ui[(x * 64 + yp) * 64 + z] - ui[(x * 64 + ym) * 64 + z]) * sy
                + (i == 1 ? 1.0f : 0.0f);
        // z-row lives entirely in this wave: lane == z
        P[i][2] = (__shfl(ctr, zp) - __shfl(ctr, zm)) * sz + (i == 2 ? 1.0f : 0.0f);
    }

    // -------- fp32 scaled-Newton polar: P <- c1*P + c2*cof(P), 8 iters ------
    // c1 = 0.5*sqrt(t/|d|), c2 = 0.5*sgn(d)/sqrt(t*|d|), t = ||cof||_F/||P||_F.
    // With cond <= ~1e4 (non-rescued lanes) intermediates stay < 1e9: safe.
    float cond_est = 0.0f;
#pragma unroll
    for (int it = 0; it < 8; ++it) {
        const float C00 = P[1][1] * P[2][2] - P[1][2] * P[2][1];
        const float C01 = P[1][2] * P[2][0] - P[1][0] * P[2][2];
        const float C02 = P[1][0] * P[2][1] - P[1][1] * P[2][0];
        const float C10 = P[0][2] * P[2][1] - P[0][1] * P[2][2];
        const float C11 = P[0][0] * P[2][2] - P[0][2] * P[2][0];
        const float C12 = P[0][1] * P[2][0] - P[0][0] * P[2][1];
        const float C20 = P[0][1] * P[1][2] - P[0][2] * P[1][1];
        const float C21 = P[0][2] * P[1][0] - P[0][0] * P[1][2];
        const float C22 = P[0][0] * P[1][1] - P[0][1] * P[1][0];
        const float det = P[0][0] * C00 + P[0][1] * C01 + P[0][2] * C02;

        const float n2 = P[0][0]*P[0][0] + P[0][1]*P[0][1] + P[0][2]*P[0][2]
                       + P[1][0]*P[1][0] + P[1][1]*P[1][1] + P[1][2]*P[1][2]
                       + P[2][0]*P[2][0] + P[2][1]*P[2][1] + P[2][2]*P[2][2];
        const float a2 = C00*C00 + C01*C01 + C02*C02
                       + C10*C10 + C11*C11 + C12*C12
                       + C20*C20 + C21*C21 + C22*C22;

        const float ad = fmaxf(fabsf(det), 1e-30f);
        if (it == 0) cond_est = sqrtf(n2 * a2) / ad;   // ||X|| ||X^-1|| (Frob)

        const float t  = fmaxf(sqrtf(a2 / n2), 1e-20f);
        const float sg = (det < 0.0f) ? -1.0f : 1.0f;
        const float c1 = 0.5f * sqrtf(t / ad);
        const float c2 = 0.5f * sg / sqrtf(t * ad);

        P[0][0] = c1 * P[0][0] + c2 * C00;  P[0][1] = c1 * P[0][1] + c2 * C01;  P[0][2] = c1 * P[0][2] + c2 * C02;
        P[1][0] = c1 * P[1][0] + c2 * C10;  P[1][1] = c1 * P[1][1] + c2 * C11;  P[1][2] = c1 * P[1][2] + c2 * C12;
        P[2][0] = c1 * P[2][0] + c2 * C20;  P[2][1] = c1 * P[2][1] + c2 * C21;  P[2][2] = c1 * P[2][2] + c2 * C22;
    }

    // -------- fp64 rescue for ill-conditioned lanes (~1e-4 of voxels) -------
    if (cond_est > 1e4f) {
        double X[3][3];
#pragma unroll
        for (int i = 0; i < 3; ++i) {
            const float* ui = db + i * NVOX;
            X[i][0] = ((double)ui[(xp * 64 + y) * 64 + z]
                     - (double)ui[(xm * 64 + y) * 64 + z]) * (double)sx + (i == 0 ? 1.0 : 0.0);
            X[i][1] = ((double)ui[(x * 64 + yp) * 64 + z]
                     - (double)ui[(x * 64 + ym) * 64 + z]) * (double)sy + (i == 1 ? 1.0 : 0.0);
            X[i][2] = ((double)ui[(x * 64 + y) * 64 + zp]
                     - (double)ui[(x * 64 + y) * 64 + zm]) * (double)sz + (i == 2 ? 1.0 : 0.0);
        }
        for (int it = 0; it < 14; ++it) {
            double mx = 0.0;
#pragma unroll
            for (int i = 0; i < 3; ++i)
#pragma unroll
                for (int j = 0; j < 3; ++j) mx = fmax(mx, fabs(X[i][j]));
            const double s = 1.0 / fmax(mx, 1e-300);
#pragma unroll
            for (int i = 0; i < 3; ++i)
#pragma unroll
                for (int j = 0; j < 3; ++j) X[i][j] *= s;

            const double C00 = X[1][1] * X[2][2] - X[1][2] * X[2][1];
            const double C01 = X[1][2] * X[2][0] - X[1][0] * X[2][2];
            const double C02 = X[1][0] * X[2][1] - X[1][1] * X[2][0];
            const double C10 = X[0][2] * X[2][1] - X[0][1] * X[2][2];
            const double C11 = X[0][0] * X[2][2] - X[0][2] * X[2][0];
            const double C12 = X[0][1] * X[2][0] - X[0][0] * X[2][1];
            const double C20 = X[0][1] * X[1][2] - X[0][2] * X[1][1];
            const double C21 = X[0][2] * X[1][0] - X[0][0] * X[1][2];
            const double C22 = X[0][0] * X[1][1] - X[0][1] * X[1][0];
            const double det = X[0][0] * C00 + X[0][1] * C01 + X[0][2] * C02;

            const double n2 = X[0][0]*X[0][0] + X[0][1]*X[0][1] + X[0][2]*X[0][2]
                            + X[1][0]*X[1][0] + X[1][1]*X[1][1] + X[1][2]*X[1][2]
                            + X[2][0]*X[2][0] + X[2][1]*X[2][1] + X[2][2]*X[2][2];
            const double a2 = C00*C00 + C01*C01 + C02*C02
                            + C10*C10 + C11*C11 + C12*C12
                            + C20*C20 + C21*C21 + C22*C22;

            const double t  = fmax(sqrt(a2 / n2), 1e-150);
            const double ad = fmax(fabs(det), 1e-280);
            const double sg = (det < 0.0) ? -1.0 : 1.0;
            const double c1 = 0.5 * sqrt(t / ad);
            const double c2 = 0.5 * sg / sqrt(t * ad);

            X[0][0] = c1 * X[0][0] + c2 * C00;  X[0][1] = c1 * X[0][1] + c2 * C01;  X[0][2] = c1 * X[0][2] + c2 * C02;
            X[1][0] = c1 * X[1][0] + c2 * C10;  X[1][1] = c1 * X[1][1] + c2 * C11;  X[1][2] = c1 * X[1][2] + c2 * C12;
            X[2][0] = c1 * X[2][0] + c2 * C20;  X[2][1] = c1 * X[2][1] + c2 * C21;  X[2][2] = c1 * X[2][2] + c2 * C22;
        }
#pragma unroll
        for (int i = 0; i < 3; ++i)
#pragma unroll
            for (int j = 0; j < 3; ++j) P[i][j] = (float)X[i][j];
    }

    // ---------------- A = R^T * M * R (fp32; R orthogonal, no blow-up) ------
    const float M3[3][3] = {{m[0], m[1], m[3]},
                            {m[1], m[2], m[4]},
                            {m[3], m[4], m[5]}};
    float T[3][3];
#pragma unroll
    for (int i = 0; i < 3; ++i)
#pragma unroll
        for (int j = 0; j < 3; ++j)
            T[i][j] = P[0][i] * M3[0][j] + P[1][i] * M3[1][j] + P[2][i] * M3[2][j];

    float A[3][3];
#pragma unroll
    for (int i = 0; i < 3; ++i)
#pragma unroll
        for (int j = 0; j < 3; ++j)
            A[i][j] = T[i][0] * P[0][j] + T[i][1] * P[1][j] + T[i][2] * P[2][j];

    // ---------------- emit lower-tri (B,6,H,W,D) fp32 ----------------
    float* ob = out + (size_t)b * 6 * NVOX;
    ob[0 * NVOX + r] = A[0][0];
    ob[1 * NVOX + r] = A[1][0];
    ob[2 * NVOX + r] = A[1][1];
    ob[3 * NVOX + r] = A[2][0];
    ob[4 * NVOX + r] = A[2][1];
    ob[5 * NVOX + r] = A[2][2];
}

extern "C" void kernel_launch(void* const* d_in, const int* in_sizes, int n_in,
                              void* d_out, int out_size, void* d_ws, size_t ws_size,
                              hipStream_t stream) {
    const float* dti = (const float*)d_in[0];
    const float* ddf = (const float*)d_in[1];
    float* out = (float*)d_out;
    warpdti_kernel<<<TOTAL / 256, 256, 0, stream>>>(dti, ddf, out);
}

// Round 6
// 108.247 us; speedup vs baseline: 1.0905x; 1.0500x over previous
//
#include <hip/hip_runtime.h>

// Problem: B=2, C=6 (DTI lower-tri), H=W=D=64. fp32 in, fp32 out.
// out[b,c,x,y,z] = (R^T M R)[I[c],J[c]]
//   M = 3x3 symmetric from trilinear-warped DTI (border clamp, align_corners)
//   R = orthogonal polar factor of J = I + du/dx  (== U @ Vh of SVD(J))
// 3-kernel pipeline (all on stream, graph-safe):
//   1. zero_count: reset bad-voxel counter in d_ws
//   2. warp_main : fp32 everything (6-iter scaled-Newton polar); lanes with
//                  cond(J) > 1e4 append voxel idx to d_ws list
//   3. rescue    : fp64 re-solve (14-iter normalized Newton) for listed voxels
// Keeping fp64 OUT of warp_main keeps its VGPR ~50 (R5's inline rescue pushed
// it to 92 and occupancy to 13% -> latency-bound at 57 us).
#define NVOX 262144          // 64^3
#define TOTAL (2 * NVOX)     // B * H * W * D threads

typedef float f2u __attribute__((ext_vector_type(2), aligned(4)));

__global__ void zero_count(int* __restrict__ bad) {
    if (threadIdx.x == 0) bad[0] = 0;
}

__global__ __launch_bounds__(256)
void warp_main(const float* __restrict__ dti,
               const float* __restrict__ ddf,
               float* __restrict__ out,
               int* __restrict__ bad, int max_bad)
{
    const int idx = blockIdx.x * 256 + threadIdx.x;   // exactly TOTAL threads
    const int b = idx >> 18;
    const int r = idx & (NVOX - 1);
    const int x = r >> 12;
    const int y = (r >> 6) & 63;
    const int z = r & 63;              // == lane (256 = 4 waves, 64 | 256)

    const float* db = ddf + (size_t)b * 3 * NVOX;

    // ---------------- displacement at center ----------------
    const float ux = db[r];
    const float uy = db[NVOX + r];
    const float uz = db[2 * NVOX + r];

    // ---------------- trilinear warp, border padding ----------------
    const float cx = fminf(fmaxf((float)x + ux, 0.0f), 63.0f);
    const float cy = fminf(fmaxf((float)y + uy, 0.0f), 63.0f);
    const float cz = fminf(fmaxf((float)z + uz, 0.0f), 63.0f);
    const float fx0 = floorf(cx), fy0 = floorf(cy), fz0 = floorf(cz);
    const float fx = cx - fx0, fy = cy - fy0, fz = cz - fz0;
    const int x0 = (int)fx0, y0 = (int)fy0, z0 = (int)fz0;
    const int x1 = min(x0 + 1, 63), y1 = min(y0 + 1, 63);

    const float gx = 1.0f - fx, gy = 1.0f - fy, gz = 1.0f - fz;
    const float q00 = gx * gy, q01 = gx * fy, q10 = fx * gy, q11 = fx * fy;

    // z0/z1 adjacent -> one 8B load per (x,y) corner per channel (24 vs 48).
    // z0==63 (only when cz==63.0, fz=0): shift base to 62, take .y for z0.
    const bool ztop = (z0 == 63);
    const int zb = ztop ? 62 : z0;
    const int p00 = (x0 * 64 + y0) * 64 + zb, p01 = (x0 * 64 + y1) * 64 + zb;
    const int p10 = (x1 * 64 + y0) * 64 + zb, p11 = (x1 * 64 + y1) * 64 + zb;

    const float* tb = dti + (size_t)b * 6 * NVOX;
    float m[6];
#pragma unroll
    for (int c = 0; c < 6; ++c) {
        const float* tc = tb + c * NVOX;
        const f2u v00 = *(const f2u*)(tc + p00);
        const f2u v01 = *(const f2u*)(tc + p01);
        const f2u v10 = *(const f2u*)(tc + p10);
        const f2u v11 = *(const f2u*)(tc + p11);
        const float l00 = (ztop ? v00.y : v00.x) * gz + v00.y * fz;
        const float l01 = (ztop ? v01.y : v01.x) * gz + v01.y * fz;
        const float l10 = (ztop ? v10.y : v10.x) * gz + v10.y * fz;
        const float l11 = (ztop ? v11.y : v11.x) * gz + v11.y * fz;
        m[c] = q00 * l00 + q01 * l01 + q10 * l10 + q11 * l11;
    }

    // -------- Jacobian J = I + du/dx (np.gradient semantics), fp32 ---------
    const int xm = max(x - 1, 0), xp = min(x + 1, 63);
    const int ym = max(y - 1, 0), yp = min(y + 1, 63);
    const int zm = max(z - 1, 0), zp = min(z + 1, 63);
    const float sx = (xp - xm == 2) ? 0.5f : 1.0f;
    const float sy = (yp - ym == 2) ? 0.5f : 1.0f;
    const float sz = (zp - zm == 2) ? 0.5f : 1.0f;

    float P[3][3];
#pragma unroll
    for (int i = 0; i < 3; ++i) {
        const float* ui = db + i * NVOX;
        const float ctr = (i == 0) ? ux : (i == 1) ? uy : uz;
        P[i][0] = (ui[(xp * 64 + y) * 64 + z] - ui[(xm * 64 + y) * 64 + z]) * sx
                + (i == 0 ? 1.0f : 0.0f);
        P[i][1] = (ui[(x * 64 + yp) * 64 + z] - ui[(x * 64 + ym) * 64 + z]) * sy
                + (i == 1 ? 1.0f : 0.0f);
        // z-row lives in this wave: lane == z
        P[i][2] = (__shfl(ctr, zp) - __shfl(ctr, zm)) * sz + (i == 2 ? 1.0f : 0.0f);
    }

    // -------- fp32 scaled-Newton polar, 6 iters (enough for cond <= 1e4) ----
    // P <- c1*P + c2*cof(P); c1 = 0.5*sqrt(t/|d|), c2 = 0.5*sgn(d)/sqrt(t|d|),
    // t = ||cof||_F/||P||_F.
    float cond_est = 0.0f;
#pragma unroll
    for (int it = 0; it < 6; ++it) {
        const float C00 = P[1][1] * P[2][2] - P[1][2] * P[2][1];
        const float C01 = P[1][2] * P[2][0] - P[1][0] * P[2][2];
        const float C02 = P[1][0] * P[2][1] - P[1][1] * P[2][0];
        const float C10 = P[0][2] * P[2][1] - P[0][1] * P[2][2];
        const float C11 = P[0][0] * P[2][2] - P[0][2] * P[2][0];
        const float C12 = P[0][1] * P[2][0] - P[0][0] * P[2][1];
        const float C20 = P[0][1] * P[1][2] - P[0][2] * P[1][1];
        const float C21 = P[0][2] * P[1][0] - P[0][0] * P[1][2];
        const float C22 = P[0][0] * P[1][1] - P[0][1] * P[1][0];
        const float det = P[0][0] * C00 + P[0][1] * C01 + P[0][2] * C02;

        const float n2 = P[0][0]*P[0][0] + P[0][1]*P[0][1] + P[0][2]*P[0][2]
                       + P[1][0]*P[1][0] + P[1][1]*P[1][1] + P[1][2]*P[1][2]
                       + P[2][0]*P[2][0] + P[2][1]*P[2][1] + P[2][2]*P[2][2];
        const float a2 = C00*C00 + C01*C01 + C02*C02
                       + C10*C10 + C11*C11 + C12*C12
                       + C20*C20 + C21*C21 + C22*C22;

        const float ad = fmaxf(fabsf(det), 1e-30f);
        if (it == 0) cond_est = sqrtf(n2 * a2) / ad;   // ~ ||X||_F ||X^-1||_F

        const float t  = fmaxf(sqrtf(a2 / n2), 1e-20f);
        const float sg = (det < 0.0f) ? -1.0f : 1.0f;
        const float c1 = 0.5f * sqrtf(t / ad);
        const float c2 = 0.5f * sg / sqrtf(t * ad);

        P[0][0] = c1 * P[0][0] + c2 * C00;  P[0][1] = c1 * P[0][1] + c2 * C01;  P[0][2] = c1 * P[0][2] + c2 * C02;
        P[1][0] = c1 * P[1][0] + c2 * C10;  P[1][1] = c1 * P[1][1] + c2 * C11;  P[1][2] = c1 * P[1][2] + c2 * C12;
        P[2][0] = c1 * P[2][0] + c2 * C20;  P[2][1] = c1 * P[2][1] + c2 * C21;  P[2][2] = c1 * P[2][2] + c2 * C22;
    }

    // ---------------- A = R^T * M * R ----------------
    const float M3[3][3] = {{m[0], m[1], m[3]},
                            {m[1], m[2], m[4]},
                            {m[3], m[4], m[5]}};
    float T[3][3];
#pragma unroll
    for (int i = 0; i < 3; ++i)
#pragma unroll
        for (int j = 0; j < 3; ++j)
            T[i][j] = P[0][i] * M3[0][j] + P[1][i] * M3[1][j] + P[2][i] * M3[2][j];

    float A[3][3];
#pragma unroll
    for (int i = 0; i < 3; ++i)
#pragma unroll
        for (int j = 0; j < 3; ++j)
            A[i][j] = T[i][0] * P[0][j] + T[i][1] * P[1][j] + T[i][2] * P[2][j];

    // ---------------- emit lower-tri (B,6,H,W,D) fp32 ----------------
    float* ob = out + (size_t)b * 6 * NVOX;
    ob[0 * NVOX + r] = A[0][0];
    ob[1 * NVOX + r] = A[1][0];
    ob[2 * NVOX + r] = A[1][1];
    ob[3 * NVOX + r] = A[2][0];
    ob[4 * NVOX + r] = A[2][1];
    ob[5 * NVOX + r] = A[2][2];

    // ---------------- flag ill-conditioned voxels for fp64 rescue -----------
    if (cond_est > 1e4f) {
        const int slot = atomicAdd(bad, 1);
        if (slot < max_bad) bad[1 + slot] = idx;
    }
}

// fp64 re-solve for the ~1e-4 fraction of voxels with near-singular J.
__global__ __launch_bounds__(256)
void rescue(const float* __restrict__ dti,
            const float* __restrict__ ddf,
            float* __restrict__ out,
            const int* __restrict__ bad, int max_bad)
{
    const int n = min(bad[0], max_bad);
    for (int k = blockIdx.x * 256 + threadIdx.x; k < n; k += 4 * 256) {
        const int idx = bad[1 + k];
        const int b = idx >> 18;
        const int r = idx & (NVOX - 1);
        const int x = r >> 12;
        const int y = (r >> 6) & 63;
        const int z = r & 63;

        const float* db = ddf + (size_t)b * 3 * NVOX;

        // warp (fp32, same as main — M is well-conditioned)
        const float cx = fminf(fmaxf((float)x + db[r], 0.0f), 63.0f);
        const float cy = fminf(fmaxf((float)y + db[NVOX + r], 0.0f), 63.0f);
        const float cz = fminf(fmaxf((float)z + db[2 * NVOX + r], 0.0f), 63.0f);
        const float fx0 = floorf(cx), fy0 = floorf(cy), fz0 = floorf(cz);
        const float fx = cx - fx0, fy = cy - fy0, fz = cz - fz0;
        const int x0 = (int)fx0, y0 = (int)fy0, z0 = (int)fz0;
        const int x1 = min(x0 + 1, 63), y1 = min(y0 + 1, 63), z1 = min(z0 + 1, 63);
        const float gx = 1.0f - fx, gy = 1.0f - fy, gz = 1.0f - fz;
        const float w000 = gx*gy*gz, w001 = gx*gy*fz, w010 = gx*fy*gz, w011 = gx*fy*fz;
        const float w100 = fx*gy*gz, w101 = fx*gy*fz, w110 = fx*fy*gz, w111 = fx*fy*fz;
        const int o000 = (x0*64+y0)*64+z0, o001 = (x0*64+y0)*64+z1;
        const int o010 = (x0*64+y1)*64+z0, o011 = (x0*64+y1)*64+z1;
        const int o100 = (x1*64+y0)*64+z0, o101 = (x1*64+y0)*64+z1;
        const int o110 = (x1*64+y1)*64+z0, o111 = (x1*64+y1)*64+z1;

        const float* tb = dti + (size_t)b * 6 * NVOX;
        float m[6];
        for (int c = 0; c < 6; ++c) {
            const float* tc = tb + c * NVOX;
            m[c] = w000*tc[o000] + w001*tc[o001] + w010*tc[o010] + w011*tc[o011]
                 + w100*tc[o100] + w101*tc[o101] + w110*tc[o110] + w111*tc[o111];
        }

        // Jacobian fp64
        const int xm = max(x-1,0), xp = min(x+1,63);
        const int ym = max(y-1,0), yp = min(y+1,63);
        const int zm = max(z-1,0), zp = min(z+1,63);
        const double sx = (xp-xm==2)?0.5:1.0, sy = (yp-ym==2)?0.5:1.0, sz = (zp-zm==2)?0.5:1.0;
        double X[3][3];
        for (int i = 0; i < 3; ++i) {
            const float* ui = db + i * NVOX;
            X[i][0] = ((double)ui[(xp*64+y)*64+z] - (double)ui[(xm*64+y)*64+z]) * sx + (i==0?1.0:0.0);
            X[i][1] = ((double)ui[(x*64+yp)*64+z] - (double)ui[(x*64+ym)*64+z]) * sy + (i==1?1.0:0.0);
            X[i][2] = ((double)ui[(x*64+y)*64+zp] - (double)ui[(x*64+y)*64+zm]) * sz + (i==2?1.0:0.0);
        }

        // 14-iter normalized scaled-Newton polar (overflow-proof)
        for (int it = 0; it < 14; ++it) {
            double mx = 0.0;
            for (int i = 0; i < 3; ++i)
                for (int j = 0; j < 3; ++j) mx = fmax(mx, fabs(X[i][j]));
            const double s = 1.0 / fmax(mx, 1e-300);
            for (int i = 0; i < 3; ++i)
                for (int j = 0; j < 3; ++j) X[i][j] *= s;

            const double C00 = X[1][1]*X[2][2] - X[1][2]*X[2][1];
            const double C01 = X[1][2]*X[2][0] - X[1][0]*X[2][2];
            const double C02 = X[1][0]*X[2][1] - X[1][1]*X[2][0];
            const double C10 = X[0][2]*X[2][1] - X[0][1]*X[2][2];
            const double C11 = X[0][0]*X[2][2] - X[0][2]*X[2][0];
            const double C12 = X[0][1]*X[2][0] - X[0][0]*X[2][1];
            const double C20 = X[0][1]*X[1][2] - X[0][2]*X[1][1];
            const double C21 = X[0][2]*X[1][0] - X[0][0]*X[1][2];
            const double C22 = X[0][0]*X[1][1] - X[0][1]*X[1][0];
            const double det = X[0][0]*C00 + X[0][1]*C01 + X[0][2]*C02;
            const double n2 = X[0][0]*X[0][0]+X[0][1]*X[0][1]+X[0][2]*X[0][2]
                            + X[1][0]*X[1][0]+X[1][1]*X[1][1]+X[1][2]*X[1][2]
                            + X[2][0]*X[2][0]+X[2][1]*X[2][1]+X[2][2]*X[2][2];
            const double a2 = C00*C00+C01*C01+C02*C02 + C10*C10+C11*C11+C12*C12
                            + C20*C20+C21*C21+C22*C22;
            const double t  = fmax(sqrt(a2 / n2), 1e-150);
            const double ad = fmax(fabs(det), 1e-280);
            const double sg = (det < 0.0) ? -1.0 : 1.0;
            const double c1 = 0.5 * sqrt(t / ad);
            const double c2 = 0.5 * sg / sqrt(t * ad);
            X[0][0]=c1*X[0][0]+c2*C00; X[0][1]=c1*X[0][1]+c2*C01; X[0][2]=c1*X[0][2]+c2*C02;
            X[1][0]=c1*X[1][0]+c2*C10; X[1][1]=c1*X[1][1]+c2*C11; X[1][2]=c1*X[1][2]+c2*C12;
            X[2][0]=c1*X[2][0]+c2*C20; X[2][1]=c1*X[2][1]+c2*C21; X[2][2]=c1*X[2][2]+c2*C22;
        }

        const double M3[3][3] = {{(double)m[0], (double)m[1], (double)m[3]},
                                 {(double)m[1], (double)m[2], (double)m[4]},
                                 {(double)m[3], (double)m[4], (double)m[5]}};
        double T[3][3], A[3][3];
        for (int i = 0; i < 3; ++i)
            for (int j = 0; j < 3; ++j)
                T[i][j] = X[0][i]*M3[0][j] + X[1][i]*M3[1][j] + X[2][i]*M3[2][j];
        for (int i = 0; i < 3; ++i)
            for (int j = 0; j < 3; ++j)
                A[i][j] = T[i][0]*X[0][j] + T[i][1]*X[1][j] + T[i][2]*X[2][j];

        float* ob = out + (size_t)b * 6 * NVOX;
        ob[0 * NVOX + r] = (float)A[0][0];
        ob[1 * NVOX + r] = (float)A[1][0];
        ob[2 * NVOX + r] = (float)A[1][1];
        ob[3 * NVOX + r] = (float)A[2][0];
        ob[4 * NVOX + r] = (float)A[2][1];
        ob[5 * NVOX + r] = (float)A[2][2];
    }
}

extern "C" void kernel_launch(void* const* d_in, const int* in_sizes, int n_in,
                              void* d_out, int out_size, void* d_ws, size_t ws_size,
                              hipStream_t stream) {
    const float* dti = (const float*)d_in[0];
    const float* ddf = (const float*)d_in[1];
    float* out = (float*)d_out;
    int* bad = (int*)d_ws;
    const int max_bad = (int)min((size_t)8192, ws_size / 4 - 1);

    zero_count<<<1, 64, 0, stream>>>(bad);
    warp_main<<<TOTAL / 256, 256, 0, stream>>>(dti, ddf, out, bad, max_bad);
    rescue<<<4, 256, 0, stream>>>(dti, ddf, out, bad, max_bad);
}